// Round 1
// baseline (110.039 us; speedup 1.0000x reference)
//
#include <hip/hip_runtime.h>
#include <hip/hip_bf16.h>
#include <float.h>

#define BB 4
#define NN 8192
#define DD 128

// ws layout:
//   [0, 2048)            : meanE sums (BB*DD = 512 floats)
//   [2048, 2048+262144)  : minbuf (2*BB*NN = 65536 uints)

__global__ void init_kernel(float* __restrict__ meanE,
                            unsigned int* __restrict__ minbuf,
                            float* __restrict__ loss_slot) {
    int i = blockIdx.x * blockDim.x + threadIdx.x;   // 65536 threads
    minbuf[i] = 0x7F7FFFFFu;                          // +FLT_MAX bit pattern
    if (i < BB * DD) meanE[i] = 0.f;
    if (i == 0) *loss_slot = 0.f;
}

// partial sums of relu(enc @ W1 + b1) over points -> meanE[b*128+k] (raw sums)
__global__ void mean_fe_kernel(const float* __restrict__ enc,
                               const float* __restrict__ W1,
                               const float* __restrict__ b1,
                               float* __restrict__ meanE) {
    __shared__ float pts[256 * 3];
    __shared__ float red[256];
    int bid = blockIdx.x;            // BB*32 blocks, 256 pts each
    int b = bid >> 5;
    int chunk = bid & 31;
    int tid = threadIdx.x;
    int k = tid & 127;
    int half = tid >> 7;
    int base = (b * NN + chunk * 256) * 3;
    for (int i = tid; i < 768; i += 256) pts[i] = enc[base + i];
    float w0 = W1[k], w1 = W1[128 + k], w2 = W1[256 + k], bk = b1[k];
    __syncthreads();
    float acc = 0.f;
    int p0 = half * 128;
#pragma unroll 4
    for (int i = 0; i < 128; ++i) {
        int p = (p0 + i) * 3;
        float v = pts[p] * w0 + pts[p + 1] * w1 + pts[p + 2] * w2 + bk;
        acc += fmaxf(v, 0.f);
    }
    red[tid] = acc;
    __syncthreads();
    if (tid < 128) atomicAdd(&meanE[b * DD + k], red[tid] + red[tid + 128]);
}

// warped = dec + b2 + f_d @ (W2lo+W2hi) + (meanE/N) @ W2lo
__global__ void warp_kernel(const float* __restrict__ dec,
                            const float* __restrict__ W1,
                            const float* __restrict__ b1,
                            const float* __restrict__ W2,
                            const float* __restrict__ b2,
                            const float* __restrict__ meanE,
                            float* __restrict__ out) {
    __shared__ float sW1[384];
    __shared__ float sb1[128];
    __shared__ float sW2[768];
    __shared__ float sME[128];
    int tid = threadIdx.x;
    int idx = blockIdx.x * 256 + tid;   // 32768 threads, one point each
    int b = idx >> 13;                  // blocks never straddle batches (256 | 8192)
    for (int i = tid; i < 384; i += 256) sW1[i] = W1[i];
    for (int i = tid; i < 768; i += 256) sW2[i] = W2[i];
    if (tid < 128) { sb1[tid] = b1[tid]; sME[tid] = meanE[b * DD + tid]; }
    __syncthreads();
    float d0 = dec[idx * 3], d1 = dec[idx * 3 + 1], d2 = dec[idx * 3 + 2];
    float a0 = 0.f, a1 = 0.f, a2 = 0.f;
    float m0 = 0.f, m1 = 0.f, m2 = 0.f;
#pragma unroll 4
    for (int k = 0; k < 128; ++k) {
        float fd = fmaxf(d0 * sW1[k] + d1 * sW1[128 + k] + d2 * sW1[256 + k] + sb1[k], 0.f);
        float wl0 = sW2[k * 3], wl1 = sW2[k * 3 + 1], wl2 = sW2[k * 3 + 2];
        float wh0 = sW2[(128 + k) * 3], wh1 = sW2[(128 + k) * 3 + 1], wh2 = sW2[(128 + k) * 3 + 2];
        a0 += fd * (wl0 + wh0);
        a1 += fd * (wl1 + wh1);
        a2 += fd * (wl2 + wh2);
        float me = sME[k];
        m0 += me * wl0; m1 += me * wl1; m2 += me * wl2;
    }
    const float invN = 1.0f / NN;
    out[idx * 3]     = a0 + m0 * invN + b2[0] + d0;
    out[idx * 3 + 1] = a1 + m1 * invN + b2[1] + d1;
    out[idx * 3 + 2] = a2 + m2 * invN + b2[2] + d2;
}

// per-x-point running min over a 1024-point y slice; combine via uint atomicMin
__global__ __launch_bounds__(256) void chamfer_min_kernel(
        const float* __restrict__ enc,
        const float* __restrict__ warped,
        unsigned int* __restrict__ minbuf) {
    __shared__ float4 sy[1024];
    int bid = blockIdx.x;       // 1024 blocks: dir(2) x b(4) x xc(16) x ys(8)
    int dir = bid >> 9;
    int rem = bid & 511;
    int b = rem >> 7;
    int rem2 = rem & 127;
    int xc = rem2 >> 3;
    int ys = rem2 & 7;
    int tid = threadIdx.x;

    const float* xsrc = (dir == 0) ? enc : warped;
    const float* ysrc = (dir == 0) ? warped : enc;

    int xbase = b * NN + xc * 512;
    int n0 = xbase + tid, n1 = n0 + 256;
    float x00 = xsrc[n0 * 3], x01 = xsrc[n0 * 3 + 1], x02 = xsrc[n0 * 3 + 2];
    float x10 = xsrc[n1 * 3], x11 = xsrc[n1 * 3 + 1], x12 = xsrc[n1 * 3 + 2];
    float xs0 = x00 * x00 + x01 * x01 + x02 * x02;
    float xs1 = x10 * x10 + x11 * x11 + x12 * x12;

    int ybase = b * NN + ys * 1024;
#pragma unroll
    for (int i = 0; i < 4; ++i) {
        int p = tid + i * 256;
        int g = (ybase + p) * 3;
        float y0 = ysrc[g], y1 = ysrc[g + 1], y2 = ysrc[g + 2];
        sy[p] = make_float4(y0, y1, y2, y0 * y0 + y1 * y1 + y2 * y2);
    }
    __syncthreads();

    float m0 = FLT_MAX, m1 = FLT_MAX, m0b = FLT_MAX, m1b = FLT_MAX;
#pragma unroll 8
    for (int j = 0; j < 1024; j += 2) {
        float4 ya = sy[j];
        float4 yb = sy[j + 1];
        float da  = x00 * ya.x + x01 * ya.y + x02 * ya.z;
        m0  = fminf(m0,  fmaf(-2.f, da,  xs0 + ya.w));
        float db  = x10 * ya.x + x11 * ya.y + x12 * ya.z;
        m1  = fminf(m1,  fmaf(-2.f, db,  xs1 + ya.w));
        float da2 = x00 * yb.x + x01 * yb.y + x02 * yb.z;
        m0b = fminf(m0b, fmaf(-2.f, da2, xs0 + yb.w));
        float db2 = x10 * yb.x + x11 * yb.y + x12 * yb.z;
        m1b = fminf(m1b, fmaf(-2.f, db2, xs1 + yb.w));
    }
    m0 = fminf(m0, m0b);
    m1 = fminf(m1, m1b);

    int slot0 = dir * (BB * NN) + b * NN + xc * 512 + tid;
    atomicMin(&minbuf[slot0], __float_as_uint(m0));
    atomicMin(&minbuf[slot0 + 256], __float_as_uint(m1));
}

__global__ void reduce_loss_kernel(const unsigned int* __restrict__ minbuf,
                                   float* __restrict__ loss_slot) {
    __shared__ float red[256];
    int tid = threadIdx.x;
    int idx = blockIdx.x * 256 + tid;   // 64 blocks
    float s = 0.f;
#pragma unroll
    for (int i = 0; i < 4; ++i)
        s += __uint_as_float(minbuf[idx + i * 16384]);
    red[tid] = s;
    __syncthreads();
    for (int off = 128; off > 0; off >>= 1) {
        if (tid < off) red[tid] += red[tid + off];
        __syncthreads();
    }
    if (tid == 0) atomicAdd(loss_slot, red[0] * (1.0f / (BB * NN)));
}

extern "C" void kernel_launch(void* const* d_in, const int* in_sizes, int n_in,
                              void* d_out, int out_size, void* d_ws, size_t ws_size,
                              hipStream_t stream) {
    const float* enc = (const float*)d_in[0];
    const float* dec = (const float*)d_in[1];
    const float* W1  = (const float*)d_in[2];
    const float* b1  = (const float*)d_in[3];
    const float* W2  = (const float*)d_in[4];
    const float* b2  = (const float*)d_in[5];
    float* out = (float*)d_out;

    float* meanE = (float*)d_ws;
    unsigned int* minbuf = (unsigned int*)((char*)d_ws + 2048);
    float* loss_slot = out + BB * NN * 3;

    init_kernel<<<256, 256, 0, stream>>>(meanE, minbuf, loss_slot);
    mean_fe_kernel<<<BB * 32, 256, 0, stream>>>(enc, W1, b1, meanE);
    warp_kernel<<<BB * NN / 256, 256, 0, stream>>>(dec, W1, b1, W2, b2, meanE, out);
    chamfer_min_kernel<<<1024, 256, 0, stream>>>(enc, out, minbuf);
    reduce_loss_kernel<<<64, 256, 0, stream>>>(minbuf, loss_slot);
}

// Round 2
// 70.818 us; speedup vs baseline: 1.5538x; 1.5538x over previous
//
#include <hip/hip_runtime.h>
#include <hip/hip_bf16.h>
#include <float.h>

#define BB 4
#define NN 8192
#define DD 128

// ws layout:
//   [0, 2048)            : meanE sums (BB*DD = 512 floats)
//   [2048, 2048+262144)  : minbuf (2*BB*NN = 65536 uints)

__global__ void init_kernel(float* __restrict__ meanE,
                            unsigned int* __restrict__ minbuf,
                            float* __restrict__ loss_slot) {
    int i = blockIdx.x * blockDim.x + threadIdx.x;   // 65536 threads
    minbuf[i] = 0x7F7FFFFFu;                          // +FLT_MAX bit pattern
    if (i < BB * DD) meanE[i] = 0.f;
    if (i == 0) *loss_slot = 0.f;
}

// partial sums of relu(enc @ W1 + b1) over points -> meanE[b*128+k] (raw sums)
__global__ void mean_fe_kernel(const float* __restrict__ enc,
                               const float* __restrict__ W1,
                               const float* __restrict__ b1,
                               float* __restrict__ meanE) {
    __shared__ float pts[256 * 3];
    __shared__ float red[256];
    int bid = blockIdx.x;            // BB*32 blocks, 256 pts each
    int b = bid >> 5;
    int chunk = bid & 31;
    int tid = threadIdx.x;
    int k = tid & 127;
    int half = tid >> 7;
    int base = (b * NN + chunk * 256) * 3;
    for (int i = tid; i < 768; i += 256) pts[i] = enc[base + i];
    float w0 = W1[k], w1 = W1[128 + k], w2 = W1[256 + k], bk = b1[k];
    __syncthreads();
    float acc = 0.f;
    int p0 = half * 128;
#pragma unroll 4
    for (int i = 0; i < 128; ++i) {
        int p = (p0 + i) * 3;
        float v = pts[p] * w0 + pts[p + 1] * w1 + pts[p + 2] * w2 + bk;
        acc += fmaxf(v, 0.f);
    }
    red[tid] = acc;
    __syncthreads();
    if (tid < 128) atomicAdd(&meanE[b * DD + k], red[tid] + red[tid + 128]);
}

// warped = dec + b2 + f_d @ (W2lo+W2hi) + (meanE/N) @ W2lo
__global__ void warp_kernel(const float* __restrict__ dec,
                            const float* __restrict__ W1,
                            const float* __restrict__ b1,
                            const float* __restrict__ W2,
                            const float* __restrict__ b2,
                            const float* __restrict__ meanE,
                            float* __restrict__ out) {
    __shared__ float sW1[384];
    __shared__ float sb1[128];
    __shared__ float sW2[768];
    __shared__ float sME[128];
    int tid = threadIdx.x;
    int idx = blockIdx.x * 256 + tid;   // 32768 threads, one point each
    int b = idx >> 13;                  // blocks never straddle batches (256 | 8192)
    for (int i = tid; i < 384; i += 256) sW1[i] = W1[i];
    for (int i = tid; i < 768; i += 256) sW2[i] = W2[i];
    if (tid < 128) { sb1[tid] = b1[tid]; sME[tid] = meanE[b * DD + tid]; }
    __syncthreads();
    float d0 = dec[idx * 3], d1 = dec[idx * 3 + 1], d2 = dec[idx * 3 + 2];
    float a0 = 0.f, a1 = 0.f, a2 = 0.f;
    float m0 = 0.f, m1 = 0.f, m2 = 0.f;
#pragma unroll 4
    for (int k = 0; k < 128; ++k) {
        float fd = fmaxf(d0 * sW1[k] + d1 * sW1[128 + k] + d2 * sW1[256 + k] + sb1[k], 0.f);
        float wl0 = sW2[k * 3], wl1 = sW2[k * 3 + 1], wl2 = sW2[k * 3 + 2];
        float wh0 = sW2[(128 + k) * 3], wh1 = sW2[(128 + k) * 3 + 1], wh2 = sW2[(128 + k) * 3 + 2];
        a0 += fd * (wl0 + wh0);
        a1 += fd * (wl1 + wh1);
        a2 += fd * (wl2 + wh2);
        float me = sME[k];
        m0 += me * wl0; m1 += me * wl1; m2 += me * wl2;
    }
    const float invN = 1.0f / NN;
    out[idx * 3]     = a0 + m0 * invN + b2[0] + d0;
    out[idx * 3 + 1] = a1 + m1 * invN + b2[1] + d1;
    out[idx * 3 + 2] = a2 + m2 * invN + b2[2] + d2;
}

// Chamfer NN-min. Per pair: t = yw - 2*x.y via 3 fma (yw folded as fma init,
// x pre-negated by 2); |x|^2 factored OUT of the min and added once at the end.
// 4 x-points per thread amortize each pair of LDS float4 broadcasts over 8 pairs.
__global__ __launch_bounds__(256) void chamfer_min_kernel(
        const float* __restrict__ enc,
        const float* __restrict__ warped,
        unsigned int* __restrict__ minbuf) {
    __shared__ float4 sy[512];
    int bid = blockIdx.x;       // 1024 blocks: dir(2) x b(4) x xc(8) x ys(16)
    int dir = bid >> 9;
    int b = (bid >> 7) & 3;
    int xc = (bid >> 4) & 7;
    int ys = bid & 15;
    int tid = threadIdx.x;

    const float* xsrc = (dir == 0) ? enc : warped;
    const float* ysrc = (dir == 0) ? warped : enc;

    int xbase = b * NN + xc * 1024;
    float xn[4][3];   // -2*x
    float xs[4];      // |x|^2
#pragma unroll
    for (int i = 0; i < 4; ++i) {
        int g = (xbase + tid + i * 256) * 3;
        float a = xsrc[g], c = xsrc[g + 1], e = xsrc[g + 2];
        xs[i] = a * a + c * c + e * e;
        xn[i][0] = -2.f * a; xn[i][1] = -2.f * c; xn[i][2] = -2.f * e;
    }

    int ybase = b * NN + ys * 512;
#pragma unroll
    for (int i = 0; i < 2; ++i) {
        int p = tid + i * 256;
        int g = (ybase + p) * 3;
        float y0 = ysrc[g], y1 = ysrc[g + 1], y2 = ysrc[g + 2];
        sy[p] = make_float4(y0, y1, y2, y0 * y0 + y1 * y1 + y2 * y2);
    }
    __syncthreads();

    float m[4] = {FLT_MAX, FLT_MAX, FLT_MAX, FLT_MAX};
#pragma unroll 4
    for (int j = 0; j < 512; j += 2) {
        float4 ya = sy[j];
        float4 yb = sy[j + 1];
#pragma unroll
        for (int i = 0; i < 4; ++i) {
            float ta = fmaf(xn[i][0], ya.x, fmaf(xn[i][1], ya.y, fmaf(xn[i][2], ya.z, ya.w)));
            float tb = fmaf(xn[i][0], yb.x, fmaf(xn[i][1], yb.y, fmaf(xn[i][2], yb.z, yb.w)));
            m[i] = fminf(m[i], fminf(ta, tb));   // hope: v_min3_f32
        }
    }

#pragma unroll
    for (int i = 0; i < 4; ++i) {
        int slot = dir * (BB * NN) + b * NN + xc * 1024 + tid + i * 256;
        atomicMin(&minbuf[slot], __float_as_uint(xs[i] + m[i]));
    }
}

__global__ void reduce_loss_kernel(const unsigned int* __restrict__ minbuf,
                                   float* __restrict__ loss_slot) {
    __shared__ float red[256];
    int tid = threadIdx.x;
    int idx = blockIdx.x * 256 + tid;   // 64 blocks
    float s = 0.f;
#pragma unroll
    for (int i = 0; i < 4; ++i)
        s += __uint_as_float(minbuf[idx + i * 16384]);
    red[tid] = s;
    __syncthreads();
    for (int off = 128; off > 0; off >>= 1) {
        if (tid < off) red[tid] += red[tid + off];
        __syncthreads();
    }
    if (tid == 0) atomicAdd(loss_slot, red[0] * (1.0f / (BB * NN)));
}

extern "C" void kernel_launch(void* const* d_in, const int* in_sizes, int n_in,
                              void* d_out, int out_size, void* d_ws, size_t ws_size,
                              hipStream_t stream) {
    const float* enc = (const float*)d_in[0];
    const float* dec = (const float*)d_in[1];
    const float* W1  = (const float*)d_in[2];
    const float* b1  = (const float*)d_in[3];
    const float* W2  = (const float*)d_in[4];
    const float* b2  = (const float*)d_in[5];
    float* out = (float*)d_out;

    float* meanE = (float*)d_ws;
    unsigned int* minbuf = (unsigned int*)((char*)d_ws + 2048);
    float* loss_slot = out + BB * NN * 3;

    init_kernel<<<256, 256, 0, stream>>>(meanE, minbuf, loss_slot);
    mean_fe_kernel<<<BB * 32, 256, 0, stream>>>(enc, W1, b1, meanE);
    warp_kernel<<<BB * NN / 256, 256, 0, stream>>>(dec, W1, b1, W2, b2, meanE, out);
    chamfer_min_kernel<<<1024, 256, 0, stream>>>(enc, out, minbuf);
    reduce_loss_kernel<<<64, 256, 0, stream>>>(minbuf, loss_slot);
}